// Round 6
// baseline (211.183 us; speedup 1.0000x reference)
//
#include <hip/hip_runtime.h>

// Bistable stochastic-resonance RK4 scan.
// x, noise: (64, 64, 4096) fp32 -> out: (64, 64, 4096) fp32
// 4096 independent sequences, one lane each; serial over T=4096.
//
// R5 lesson: R2 (divergent loads) and R5 (pure LDS compute wave) both land
// at 117 cyc/step -> bound by the serial dependent-FMA chain (12 ops x ~9.7
// cyc lone-wave latency), not memory. R6: restructure RK4 to the provable
// 8-op critical path:
//   per stage: y' = fma(-h*y, y^2, c') with c' = fma(..., y, i-terms) at
//   depth+1 -> 2 chain ops/stage (square, fma), 4 stages = 8.
//   ksum eliminated: k1+2k2+2k3 = (2/h)(y2+2y3+y4-4s); k4 + y4-linear terms
//   fold into the final fma: s' = fma(-H6*y4, y4^2, QQ).
// Producer/consumer structure kept from R5 (wave 0 compute: LDS+VALU only;
// wave 1: coalesced loads/stores, reg-pipelined one tile ahead).

#define T_STEPS 4096
#define N_SEQ   4096
#define TILE    32
#define NT      (T_STEPS / TILE)      // 128 tiles
#define ROW_BYTES (T_STEPS * 4)       // 16384 B per sequence stream
#define TB      (TILE * 4)            // 128 B per row per tile

typedef float f32x4 __attribute__((ext_vector_type(4)));

// 8-dependent-op RK4 step (critical path: s->u1->y2->u2->y3->u3->y4->u4->s')
__device__ __forceinline__ float rk4_step(float s, float i, float n) {
    const float H   = 0.01f;              // dt
    const float H2  = 0.005f;             // dt/2
    const float H6  = 0.01f / 6.0f;       // dt/6
    const float SD  = 0.1f;               // sqrt(dt)
    const float A2  = 1.0f + H2;          // 1.005
    const float C3  = 1.0f / 3.0f;
    const float CQ  = C3 + H6;            // 1/3 + dt/6

    // depth-0: input-only precomputes (off chain)
    float hi2 = H2 * i;
    float pre = fmaf(H6, i, SD * n);      // H6*i + SD*n

    // depth-1: one op from s
    float u1  = s * s;
    float c1p = fmaf(A2, s, hi2);         // s(1+H2) + H2*i
    float p1  = H2 * s;
    float bs  = fmaf(-C3, s, pre);        // -s/3 + SD*n + H6*i
    float cs2 = fmaf(H2, i, s);           // s + H2*i
    float cs3 = fmaf(H,  i, s);           // s + H*i

    // depth-2: y2 = s + H2*k1 = c1p - p1*u1
    float y2  = fmaf(-p1, u1, c1p);

    // depth-3
    float u2  = y2 * y2;
    float c2p = fmaf(H2, y2, cs2);
    float p2  = H2 * y2;

    // depth-4: y3 = s + H2*k2
    float y3  = fmaf(-p2, u2, c2p);

    // depth-5
    float u3  = y3 * y3;
    float c3p = fmaf(H, y3, cs3);
    float p3  = H * y3;
    float G   = fmaf(2.0f, y3, y2);       // y2 + 2*y3

    // depth-6: y4 = s + H*k3 ; Q = (y2+2y3)/3 - s/3 + SD*n + H6*i
    float y4  = fmaf(-p3, u3, c3p);
    float Q   = fmaf(C3, G, bs);

    // depth-7
    float u4  = y4 * y4;
    float z   = H6 * y4;
    float QQ  = fmaf(CQ, y4, Q);          // + (1/3+H6)*y4

    // depth-8: s' = QQ - H6*y4^3
    return fmaf(-z, u4, QQ);
}

__global__ __launch_bounds__(128, 1) void bistable_sr_kernel(
        const float* __restrict__ x,
        const float* __restrict__ noise,
        float* __restrict__ out) {
    __shared__ f32x4 ibx[2][512];
    __shared__ f32x4 ibn[2][512];
    __shared__ f32x4 obf[2][512];

    const int tid = threadIdx.x;
    const int wid = tid >> 6;        // 0 = compute, 1 = memory
    const int l   = tid & 63;
    const size_t sb = (size_t)blockIdx.x * 64;

    const char* xb = (const char*)(x + sb * T_STEPS);
    const char* nb = (const char*)(noise + sb * T_STEPS);
    char*       ob = (char*)(out + sb * T_STEPS);

    int goff[8];
#pragma unroll
    for (int k = 0; k < 8; ++k) {
        const int r = 8 * k + (l >> 3);
        goff[k] = r * ROW_BYTES + (((l & 7) ^ (r & 7)) << 4);
    }

    f32x4 xr[8], nr[8];
    if (wid == 1) {
#pragma unroll
        for (int k = 0; k < 8; ++k) {
            xr[k] = *(const f32x4*)(xb + goff[k]);
            nr[k] = *(const f32x4*)(nb + goff[k]);
        }
#pragma unroll
        for (int k = 0; k < 8; ++k) {
            ibx[0][k * 64 + l] = xr[k];
            ibn[0][k * 64 + l] = nr[k];
        }
#pragma unroll
        for (int k = 0; k < 8; ++k) {
            xr[k] = *(const f32x4*)(xb + goff[k] + TB);
            nr[k] = *(const f32x4*)(nb + goff[k] + TB);
        }
    }

    const int xorl = l & 7;
    float s = 0.0f;

    __syncthreads();                 // tile 0 staged

    for (int tau = 0; tau < NT; ++tau) {
        const int b = tau & 1;
        if (wid == 0) {
            const f32x4* px = &ibx[b][l * 8];
            const f32x4* pn = &ibn[b][l * 8];
            f32x4*       po = &obf[b][l * 8];

            f32x4 xv = px[0 ^ xorl], nv = pn[0 ^ xorl];
#pragma unroll
            for (int j = 0; j < 8; ++j) {
                f32x4 xv2, nv2;
                if (j < 7) {                 // static unroll: reg pipeline
                    xv2 = px[(j + 1) ^ xorl];
                    nv2 = pn[(j + 1) ^ xorl];
                }
                f32x4 o;
                s = rk4_step(s, xv.x, nv.x); o.x = s;
                s = rk4_step(s, xv.y, nv.y); o.y = s;
                s = rk4_step(s, xv.z, nv.z); o.z = s;
                s = rk4_step(s, xv.w, nv.w); o.w = s;
                po[j ^ xorl] = o;
                xv = xv2; nv = nv2;
            }
        } else {
            if (tau + 1 < NT) {
#pragma unroll
                for (int k = 0; k < 8; ++k) {
                    ibx[b ^ 1][k * 64 + l] = xr[k];
                    ibn[b ^ 1][k * 64 + l] = nr[k];
                }
                if (tau + 2 < NT) {
#pragma unroll
                    for (int k = 0; k < 8; ++k) {
                        xr[k] = *(const f32x4*)(xb + goff[k] + (tau + 2) * TB);
                        nr[k] = *(const f32x4*)(nb + goff[k] + (tau + 2) * TB);
                    }
                }
            }
            if (tau >= 1) {
#pragma unroll
                for (int k = 0; k < 8; ++k) {
                    f32x4 v = obf[(tau - 1) & 1][k * 64 + l];
                    *(f32x4*)(ob + goff[k] + (tau - 1) * TB) = v;
                }
            }
        }
        __syncthreads();
    }

    if (wid == 1) {
#pragma unroll
        for (int k = 0; k < 8; ++k) {
            f32x4 v = obf[(NT - 1) & 1][k * 64 + l];
            *(f32x4*)(ob + goff[k] + (NT - 1) * TB) = v;
        }
    }
}

extern "C" void kernel_launch(void* const* d_in, const int* in_sizes, int n_in,
                              void* d_out, int out_size, void* d_ws, size_t ws_size,
                              hipStream_t stream) {
    const float* x     = (const float*)d_in[0];
    const float* noise = (const float*)d_in[1];
    float* out = (float*)d_out;

    dim3 grid(N_SEQ / 64);
    dim3 block(128);
    bistable_sr_kernel<<<grid, block, 0, stream>>>(x, noise, out);
}

// Round 7
// 198.996 us; speedup vs baseline: 1.0612x; 1.0612x over previous
//
#include <hip/hip_runtime.h>

// Bistable stochastic-resonance RK4 scan.
// x, noise: (64, 64, 4096) fp32 -> out: (64, 64, 4096) fp32
// 4096 independent sequences, one lane each; serial over T=4096.
//
// R5/R6 lesson: per-step cost ~= (VALU instr count) x ~4.6 cyc, independent
// of chain depth (12 vs 8) and memory structure -> lone-wave ISSUE-CADENCE
// bound (CU sequencer round-robins SIMDs; a solo wave issues ~1 instr/4cyc).
// R7: minimize instructions/step: 21 scalar ops (depth-8 chain kept) +
// input-only precomputes vectorized as f32x4 (v_pk_* pairs) + 2-ahead LDS
// read prefetch. Producer/consumer structure from R5 unchanged.

#define T_STEPS 4096
#define N_SEQ   4096
#define TILE    32
#define NT      (T_STEPS / TILE)      // 128 tiles
#define ROW_BYTES (T_STEPS * 4)       // 16384 B per sequence stream
#define TB      (TILE * 4)            // 128 B per row per tile

typedef float f32x4 __attribute__((ext_vector_type(4)));

// 21-op RK4 step; inputs: state s, i = x_t, hi2 = H2*i (precomputed vec),
// A = H6*i + SD*n (precomputed vec). Critical path 8 ops:
// s->u1->y2->u2->y3->u3->y4->u4->s'
__device__ __forceinline__ float rk4_step(float s, float i, float hi2, float A) {
    const float H   = 0.01f;
    const float H2  = 0.005f;
    const float H6  = 0.01f / 6.0f;
    const float A2  = 1.0f + H2;
    const float C3  = 1.0f / 3.0f;
    const float C32 = 2.0f / 3.0f;
    const float CQ  = C3 + H6;

    float cs2 = fmaf(H2, i, s);           // s + H2*i
    float cs3 = fmaf(H,  i, s);           // s + H*i
    float bs  = fmaf(-C3, s, A);          // -s/3 + H6*i + SD*n

    float u1  = s * s;
    float p1  = H2 * s;
    float c1  = fmaf(A2, s, hi2);         // (1+H2)s + H2*i
    float y2  = fmaf(-p1, u1, c1);        // s + H2*f(s)

    float u2  = y2 * y2;
    float p2  = H2 * y2;
    float c2  = fmaf(H2, y2, cs2);
    float bs2 = fmaf(C3, y2, bs);         // early Q accumulation (fills stalls)
    float y3  = fmaf(-p2, u2, c2);        // s + H2*f(y2)

    float u3  = y3 * y3;
    float p3  = H * y3;
    float c3  = fmaf(H, y3, cs3);
    float Q   = fmaf(C32, y3, bs2);       // C3*(y2+2y3) - s/3 + H6*i + SD*n
    float y4  = fmaf(-p3, u3, c3);        // s + H*f(y3)

    float u4  = y4 * y4;
    float z   = H6 * y4;
    float QQ  = fmaf(CQ, y4, Q);          // + (1/3 + H6)*y4
    return fmaf(-z, u4, QQ);              // - H6*y4^3
}

__global__ __launch_bounds__(128, 1) void bistable_sr_kernel(
        const float* __restrict__ x,
        const float* __restrict__ noise,
        float* __restrict__ out) {
    __shared__ f32x4 ibx[2][512];
    __shared__ f32x4 ibn[2][512];
    __shared__ f32x4 obf[2][512];

    const int tid = threadIdx.x;
    const int wid = tid >> 6;        // 0 = compute, 1 = memory
    const int l   = tid & 63;
    const size_t sb = (size_t)blockIdx.x * 64;

    const char* xb = (const char*)(x + sb * T_STEPS);
    const char* nb = (const char*)(noise + sb * T_STEPS);
    char*       ob = (char*)(out + sb * T_STEPS);

    int goff[8];
#pragma unroll
    for (int k = 0; k < 8; ++k) {
        const int r = 8 * k + (l >> 3);
        goff[k] = r * ROW_BYTES + (((l & 7) ^ (r & 7)) << 4);
    }

    f32x4 xr[8], nr[8];
    if (wid == 1) {
#pragma unroll
        for (int k = 0; k < 8; ++k) {
            xr[k] = *(const f32x4*)(xb + goff[k]);
            nr[k] = *(const f32x4*)(nb + goff[k]);
        }
#pragma unroll
        for (int k = 0; k < 8; ++k) {
            ibx[0][k * 64 + l] = xr[k];
            ibn[0][k * 64 + l] = nr[k];
        }
#pragma unroll
        for (int k = 0; k < 8; ++k) {
            xr[k] = *(const f32x4*)(xb + goff[k] + TB);
            nr[k] = *(const f32x4*)(nb + goff[k] + TB);
        }
    }

    const int xorl = l & 7;
    float s = 0.0f;

    const f32x4 vH2 = {0.005f, 0.005f, 0.005f, 0.005f};
    const f32x4 vSD = {0.1f, 0.1f, 0.1f, 0.1f};
    const f32x4 vC3 = {1.0f/3.0f, 1.0f/3.0f, 1.0f/3.0f, 1.0f/3.0f};

    __syncthreads();                 // tile 0 staged

    for (int tau = 0; tau < NT; ++tau) {
        const int b = tau & 1;
        if (wid == 0) {
            const f32x4* px = &ibx[b][l * 8];
            const f32x4* pn = &ibn[b][l * 8];
            f32x4*       po = &obf[b][l * 8];

            // 2-deep register pipeline of LDS reads (all indices static).
            f32x4 xv0 = px[0 ^ xorl], nv0 = pn[0 ^ xorl];
            f32x4 xv1 = px[1 ^ xorl], nv1 = pn[1 ^ xorl];
#pragma unroll
            for (int j = 0; j < 8; ++j) {
                f32x4 xv = xv0, nv = nv0;
                xv0 = xv1; nv0 = nv1;
                if (j < 6) {
                    xv1 = px[(j + 2) ^ xorl];
                    nv1 = pn[(j + 2) ^ xorl];
                }
                // input-only precomputes, vectorized (v_pk_*):
                f32x4 hi2v = xv * vH2;                              // H2*i
                f32x4 sdnv = nv * vSD;                              // SD*n
                f32x4 Av   = __builtin_elementwise_fma(vC3, hi2v, sdnv); // H6*i+SD*n

                f32x4 o;
                s = rk4_step(s, xv.x, hi2v.x, Av.x); o.x = s;
                s = rk4_step(s, xv.y, hi2v.y, Av.y); o.y = s;
                s = rk4_step(s, xv.z, hi2v.z, Av.z); o.z = s;
                s = rk4_step(s, xv.w, hi2v.w, Av.w); o.w = s;
                po[j ^ xorl] = o;
            }
        } else {
            if (tau + 1 < NT) {
#pragma unroll
                for (int k = 0; k < 8; ++k) {
                    ibx[b ^ 1][k * 64 + l] = xr[k];
                    ibn[b ^ 1][k * 64 + l] = nr[k];
                }
                if (tau + 2 < NT) {
#pragma unroll
                    for (int k = 0; k < 8; ++k) {
                        xr[k] = *(const f32x4*)(xb + goff[k] + (tau + 2) * TB);
                        nr[k] = *(const f32x4*)(nb + goff[k] + (tau + 2) * TB);
                    }
                }
            }
            if (tau >= 1) {
#pragma unroll
                for (int k = 0; k < 8; ++k) {
                    f32x4 v = obf[(tau - 1) & 1][k * 64 + l];
                    *(f32x4*)(ob + goff[k] + (tau - 1) * TB) = v;
                }
            }
        }
        __syncthreads();
    }

    if (wid == 1) {
#pragma unroll
        for (int k = 0; k < 8; ++k) {
            f32x4 v = obf[(NT - 1) & 1][k * 64 + l];
            *(f32x4*)(ob + goff[k] + (NT - 1) * TB) = v;
        }
    }
}

extern "C" void kernel_launch(void* const* d_in, const int* in_sizes, int n_in,
                              void* d_out, int out_size, void* d_ws, size_t ws_size,
                              hipStream_t stream) {
    const float* x     = (const float*)d_in[0];
    const float* noise = (const float*)d_in[1];
    float* out = (float*)d_out;

    dim3 grid(N_SEQ / 64);
    dim3 block(128);
    bistable_sr_kernel<<<grid, block, 0, stream>>>(x, noise, out);
}